// Round 6
// baseline (1236.824 us; speedup 1.0000x reference)
//
#include <hip/hip_runtime.h>

#define H  64
#define G4 256   // 4*H

// fast sigmoid/tanh: v_exp_f32 + v_rcp_f32. Safe at +-inf:
//   x->-inf: exp(-x)=inf -> rcp(inf)=0 ; x->+inf: exp(-x)=0 -> rcp(1)=1
__device__ __forceinline__ float sigm(float x) {
    return __builtin_amdgcn_rcpf(1.0f + __expf(-x));
}
__device__ __forceinline__ float tanh_s(float x) {
    return fmaf(2.0f, sigm(2.0f * x), -1.0f);
}

__device__ __forceinline__ float bcast(float v, int lane) {
    return __int_as_float(__builtin_amdgcn_readlane(__float_as_int(v), lane));
}

// X-macro over 0..63 (64 named scalars)
#define R64(M) \
  M(0) M(1) M(2) M(3) M(4) M(5) M(6) M(7) M(8) M(9) M(10) M(11) M(12) M(13) M(14) M(15) \
  M(16) M(17) M(18) M(19) M(20) M(21) M(22) M(23) M(24) M(25) M(26) M(27) M(28) M(29) M(30) M(31) \
  M(32) M(33) M(34) M(35) M(36) M(37) M(38) M(39) M(40) M(41) M(42) M(43) M(44) M(45) M(46) M(47) \
  M(48) M(49) M(50) M(51) M(52) M(53) M(54) M(55) M(56) M(57) M(58) M(59) M(60) M(61) M(62) M(63)

// P[v][g] = sum_h table[v][h] * w_ih[g][h] + b_ih[g] + b_hh[g], table[0] = 0
// blockIdx.y = 0 -> forward params, 1 -> backward params.
__global__ __launch_bounds__(256)
void proj_kernel(const float* __restrict__ emb,
                 const float* __restrict__ w_ih_f,
                 const float* __restrict__ b_ih_f,
                 const float* __restrict__ b_hh_f,
                 const float* __restrict__ w_ih_b,
                 const float* __restrict__ b_ih_b,
                 const float* __restrict__ b_hh_b,
                 float* __restrict__ Pf,
                 float* __restrict__ Pb,
                 int V)
{
    const int j  = threadIdx.x;       // output gate index 0..255
    const int v0 = blockIdx.x * 8;
    const bool bwd = (blockIdx.y != 0);

    const float* __restrict__ w_ih = bwd ? w_ih_b : w_ih_f;
    const float* __restrict__ b_ih = bwd ? b_ih_b : b_ih_f;
    const float* __restrict__ b_hh = bwd ? b_hh_b : b_hh_f;
    float* __restrict__ P          = bwd ? Pb     : Pf;

    __shared__ float es[8][H];
    // cooperative load of 8 embedding rows (512 floats, 2 per thread)
    {
        int idx = j;
        #pragma unroll
        for (int rep = 0; rep < 2; ++rep, idx += 256) {
            int r = idx >> 6, col = idx & 63;
            int v = v0 + r;
            float val = 0.0f;
            if (v < V && v != 0) val = emb[v * H + col];   // padding_idx=0
            es[r][col] = val;
        }
    }

    float w[H];
    const float4* w4 = reinterpret_cast<const float4*>(w_ih + j * H);
    #pragma unroll
    for (int i = 0; i < 16; ++i) {
        float4 t = w4[i];
        w[4*i] = t.x; w[4*i+1] = t.y; w[4*i+2] = t.z; w[4*i+3] = t.w;
    }
    float bias = b_ih[j] + b_hh[j];
    __syncthreads();

    #pragma unroll
    for (int r = 0; r < 8; ++r) {
        int v = v0 + r;
        if (v >= V) break;
        float a0 = 0, a1 = 0, a2 = 0, a3 = 0;
        #pragma unroll
        for (int k = 0; k < H; k += 4) {
            a0 = fmaf(es[r][k+0], w[k+0], a0);
            a1 = fmaf(es[r][k+1], w[k+1], a1);
            a2 = fmaf(es[r][k+2], w[k+2], a2);
            a3 = fmaf(es[r][k+3], w[k+3], a3);
        }
        P[v * G4 + j] = bias + ((a0 + a1) + (a2 + a3));
    }
}

// One block per batch element. 4 waves; wave w owns gate w (rows 64w..64w+63
// of w_hh), parked in AGPRs.
//
// Evidence trail:
//  - R1/R2/R4/R5: any plain-VGPR formulation -> RA remats the (invariant)
//    loads every step; VGPR_Count=40; 1117 cyc/step == per-XCD L2 roofline
//    for the 64KB/step refetch (32 CU x 64KB / 4.3TB/s ~= 1170 cyc).
//  - R3: AGPR park via asm volatile write+read DID hold (VGPR=116) but the
//    64 per-step VOLATILE reads serialized the scheduler -> 1450 cyc/step.
// This version: volatile writes (once, pre-loop, proven to stick) +
// NON-volatile reads with a dummy loop-carried operand (h) so they can be
// scheduled/interleaved but never hoisted out of the loop.
__global__ __launch_bounds__(256, 1)
void lstm_kernel(const int* __restrict__ x,      // [B,T]
                 const float* __restrict__ Pf,   // [V,4H]
                 const float* __restrict__ Pb,   // [V,4H]
                 const float* __restrict__ w_hh, // [4H,H] (forward)
                 const float* __restrict__ w_fc, // [12,2H]
                 const float* __restrict__ b_fc, // [12]
                 float* __restrict__ out,        // [B,12]
                 int T)
{
    const int b    = blockIdx.x;
    const int j    = threadIdx.x;   // gate-output row 0..255
    const int lane = j & 63;
    const int gate = j >> 6;        // == wave id: 0=i 1=f 2=g 3=o

    // load per-thread recurrent weight row, then park all 64 in AGPRs
    float lw[H];
    const float4* w4 = reinterpret_cast<const float4*>(w_hh + j * H);
    #pragma unroll
    for (int i = 0; i < 16; ++i) {
        float4 t = w4[i];
        lw[4*i] = t.x; lw[4*i+1] = t.y; lw[4*i+2] = t.z; lw[4*i+3] = t.w;
    }

    #define WDECL(i) float wa_##i;
    R64(WDECL)
    #undef WDECL
    #define WWRITE(i) asm volatile("v_accvgpr_write_b32 %0, %1" : "=a"(wa_##i) : "v"(lw[i]));
    R64(WWRITE)
    #undef WWRITE

    // branchless activation: act = Aa * sigm(ms*s) + Ba
    const float ms = (gate == 2) ? 2.0f : 1.0f;
    const float Aa = (gate == 2) ? 2.0f : 1.0f;
    const float Ba = (gate == 2) ? -1.0f : 0.0f;

    __shared__ float g_s[2][G4];
    __shared__ float hf_s[H];
    __shared__ float hb_s[H];

    const int* __restrict__ xrow = x + (long)b * T;

    float h = 0.0f;   // lane's h value (replicated across all 4 waves)
    float c = 0.0f;

    int   tok_next = (T > 1) ? xrow[1] : 0;
    float p_cur    = Pf[xrow[0] * G4 + j];

    for (int t = 0; t < T; ++t) {
        // prefetch next timestep's projected input (L2-resident gather)
        float p_next = 0.0f;
        if (t + 1 < T) p_next = Pf[tok_next * G4 + j];
        int tok_next2 = (t + 2 < T) ? xrow[t + 2] : 0;

        // s = p_cur + sum_k w[k] * h[k]
        // Weights stream out of AGPRs via NON-volatile asm reads:
        //  - dummy "v"(h) input (loop-carried) forbids hoisting/CSE across
        //    iterations, distinct wa_i forbids CSE within one
        //  - no volatile => scheduler interleaves read/readlane/fma freely
        float acc[4] = {0.0f, 0.0f, 0.0f, 0.0f};
        #define WSTEP(i) { float t_;                                          \
            asm("v_accvgpr_read_b32 %0, %1"                                   \
                : "=v"(t_) : "a"(wa_##i), "v"(h));                            \
            acc[(i) & 3] = fmaf(t_, bcast(h, (i)), acc[(i) & 3]); }
        R64(WSTEP)
        #undef WSTEP

        float s   = p_cur + ((acc[0] + acc[1]) + (acc[2] + acc[3]));
        float act = fmaf(Aa, sigm(ms * s), Ba);

        const int ph = t & 1;
        g_s[ph][j] = act;
        __syncthreads();   // the single per-step barrier (gate exchange)

        float gi = g_s[ph][lane];
        float gf = g_s[ph][H   + lane];
        float gg = g_s[ph][2*H + lane];
        float go = g_s[ph][3*H + lane];
        c = fmaf(gf, c, gi * gg);
        h = go * tanh_s(c);

        p_cur    = p_next;
        tok_next = tok_next2;
    }

    __syncthreads();   // protect g_s[0] reuse below

    // backward LSTM: exactly one step (hs_b[0]) with zero initial state
    {
        int   tokL = xrow[T - 1];
        float gb   = Pb[tokL * G4 + j];
        g_s[0][j]  = fmaf(Aa, sigm(ms * gb), Ba);
    }
    if (gate == 0) hf_s[lane] = h;
    __syncthreads();

    if (j < H) {
        float i_ = g_s[0][j];
        float gg = g_s[0][2*H + j];
        float go = g_s[0][3*H + j];
        float cb = i_ * gg;               // f*c0 = 0
        hb_s[j] = go * tanh_s(cb);
    }
    __syncthreads();

    // final FC: y[b, j] = b_fc[j] + [h_f | h_b] . w_fc[j]
    if (j < 12) {
        float acc = b_fc[j];
        const float* wf = w_fc + j * (2 * H);
        #pragma unroll
        for (int k = 0; k < H; ++k) acc = fmaf(hf_s[k], wf[k], acc);
        #pragma unroll
        for (int k = 0; k < H; ++k) acc = fmaf(hb_s[k], wf[H + k], acc);
        out[b * 12 + j] = acc;
    }
}

extern "C" void kernel_launch(void* const* d_in, const int* in_sizes, int n_in,
                              void* d_out, int out_size, void* d_ws, size_t ws_size,
                              hipStream_t stream)
{
    const int*   x      = (const int*)  d_in[0];
    const float* emb    = (const float*)d_in[1];
    const float* w_ih_f = (const float*)d_in[2];
    const float* w_hh_f = (const float*)d_in[3];
    const float* b_ih_f = (const float*)d_in[4];
    const float* b_hh_f = (const float*)d_in[5];
    const float* w_ih_b = (const float*)d_in[6];
    // d_in[7] = w_hh_b (unused: backward runs exactly one step from zero state)
    const float* b_ih_b = (const float*)d_in[8];
    const float* b_hh_b = (const float*)d_in[9];
    const float* w_fc   = (const float*)d_in[10];
    const float* b_fc   = (const float*)d_in[11];
    float* out = (float*)d_out;

    const int B = out_size / 12;
    const int T = in_sizes[0] / B;
    const int V = in_sizes[1] / H;

    float* Pf = (float*)d_ws;                   // [V,4H]
    float* Pb = Pf + (size_t)V * G4;            // [V,4H]  (4 MB total)

    int pblocks = (V + 7) / 8;
    dim3 pgrid(pblocks, 2);
    proj_kernel<<<pgrid, 256, 0, stream>>>(emb, w_ih_f, b_ih_f, b_hh_f,
                                           w_ih_b, b_ih_b, b_hh_b, Pf, Pb, V);
    lstm_kernel<<<B, 256, 0, stream>>>(x, Pf, Pb, w_hh_f, w_fc, b_fc, out, T);
}

// Round 7
// 1176.770 us; speedup vs baseline: 1.0510x; 1.0510x over previous
//
#include <hip/hip_runtime.h>

#define H  64
#define G4 256   // 4*H

// fast sigmoid/tanh: v_exp_f32 + v_rcp_f32. Safe at +-inf:
//   x->-inf: exp(-x)=inf -> rcp(inf)=0 ; x->+inf: exp(-x)=0 -> rcp(1)=1
__device__ __forceinline__ float sigm(float x) {
    return __builtin_amdgcn_rcpf(1.0f + __expf(-x));
}
__device__ __forceinline__ float tanh_s(float x) {
    return fmaf(2.0f, sigm(2.0f * x), -1.0f);
}

// P[v][g] = sum_h table[v][h] * w_ih[g][h] + b_ih[g] + b_hh[g], table[0] = 0
// blockIdx.y = 0 -> forward params, 1 -> backward params.
__global__ __launch_bounds__(256)
void proj_kernel(const float* __restrict__ emb,
                 const float* __restrict__ w_ih_f,
                 const float* __restrict__ b_ih_f,
                 const float* __restrict__ b_hh_f,
                 const float* __restrict__ w_ih_b,
                 const float* __restrict__ b_ih_b,
                 const float* __restrict__ b_hh_b,
                 float* __restrict__ Pf,
                 float* __restrict__ Pb,
                 int V)
{
    const int j  = threadIdx.x;       // output gate index 0..255
    const int v0 = blockIdx.x * 8;
    const bool bwd = (blockIdx.y != 0);

    const float* __restrict__ w_ih = bwd ? w_ih_b : w_ih_f;
    const float* __restrict__ b_ih = bwd ? b_ih_b : b_ih_f;
    const float* __restrict__ b_hh = bwd ? b_hh_b : b_hh_f;
    float* __restrict__ P          = bwd ? Pb     : Pf;

    __shared__ float es[8][H];
    // cooperative load of 8 embedding rows (512 floats, 2 per thread)
    {
        int idx = j;
        #pragma unroll
        for (int rep = 0; rep < 2; ++rep, idx += 256) {
            int r = idx >> 6, col = idx & 63;
            int v = v0 + r;
            float val = 0.0f;
            if (v < V && v != 0) val = emb[v * H + col];   // padding_idx=0
            es[r][col] = val;
        }
    }

    float w[H];
    const float4* w4 = reinterpret_cast<const float4*>(w_ih + j * H);
    #pragma unroll
    for (int i = 0; i < 16; ++i) {
        float4 t = w4[i];
        w[4*i] = t.x; w[4*i+1] = t.y; w[4*i+2] = t.z; w[4*i+3] = t.w;
    }
    float bias = b_ih[j] + b_hh[j];
    __syncthreads();

    #pragma unroll
    for (int r = 0; r < 8; ++r) {
        int v = v0 + r;
        if (v >= V) break;
        float a0 = 0, a1 = 0, a2 = 0, a3 = 0;
        #pragma unroll
        for (int k = 0; k < H; k += 4) {
            a0 = fmaf(es[r][k+0], w[k+0], a0);
            a1 = fmaf(es[r][k+1], w[k+1], a1);
            a2 = fmaf(es[r][k+2], w[k+2], a2);
            a3 = fmaf(es[r][k+3], w[k+3], a3);
        }
        P[v * G4 + j] = bias + ((a0 + a1) + (a2 + a3));
    }
}

// One block per batch element. 4 waves; wave w owns gate w (rows 64w..64w+63
// of w_hh). Two structural fixes from the R1-R6 evidence trail:
//
//  1) Weight residency: w_hh is staged into LDS once, and each thread loads
//     its row into 16 NAMED float4s. R1/R2/R4/R5 proved the compiler remats
//     invariant GLOBAL loads every step (VGPR=40, 64KB/step refetch = 1117
//     cyc/step); a ds_read is never rematerializable (LDS is mutable, g_s
//     writes alias it) and cannot be sunk into the loop, so the 64 values
//     MUST stay live in VGPRs (budget 512 at occupancy 1).
//  2) h broadcast via per-wave LDS copy (16 uniform-address ds_read_b128)
//     instead of 64 v_readlane (~4cyc each, ~256 cyc/step -- R1/R6 VALU
//     accounting). Own-wave h_s write->read needs NO barrier (DS unit is
//     in-order per wave); the cross-wave g_s exchange keeps the single
//     per-step barrier.
__global__ __launch_bounds__(256, 1)
void lstm_kernel(const int* __restrict__ x,      // [B,T]
                 const float* __restrict__ Pf,   // [V,4H]
                 const float* __restrict__ Pb,   // [V,4H]
                 const float* __restrict__ w_hh, // [4H,H] (forward)
                 const float* __restrict__ w_fc, // [12,2H]
                 const float* __restrict__ b_fc, // [12]
                 float* __restrict__ out,        // [B,12]
                 int T)
{
    const int b    = blockIdx.x;
    const int j    = threadIdx.x;   // gate-output row 0..255
    const int lane = j & 63;
    const int gate = j >> 6;        // == wave id: 0=i 1=f 2=g 3=o

    __shared__ float w_lds[G4 * H];   // 64 KB: full w_hh
    __shared__ float g_s[2][G4];
    __shared__ float h_s[4 * H];      // per-wave private h copy
    __shared__ float hf_s[H];
    __shared__ float hb_s[H];

    // cooperative, coalesced staging of w_hh into LDS (one time)
    {
        const float4* src = reinterpret_cast<const float4*>(w_hh);
        float4*       dst = reinterpret_cast<float4*>(w_lds);
        #pragma unroll
        for (int r = 0; r < 16; ++r) dst[r * 256 + j] = src[r * 256 + j];
    }
    h_s[j] = 0.0f;                    // zero all 4 per-wave h copies
    __syncthreads();

    // per-thread recurrent weight row out of LDS -> 16 named float4 in VGPRs
    const float4* wl = reinterpret_cast<const float4*>(w_lds + j * H);
    float4 q0  = wl[0],  q1  = wl[1],  q2  = wl[2],  q3  = wl[3];
    float4 q4  = wl[4],  q5  = wl[5],  q6  = wl[6],  q7  = wl[7];
    float4 q8  = wl[8],  q9  = wl[9],  q10 = wl[10], q11 = wl[11];
    float4 q12 = wl[12], q13 = wl[13], q14 = wl[14], q15 = wl[15];

    // branchless activation: act = Aa * sigm(ms*s) + Ba
    const float ms = (gate == 2) ? 2.0f : 1.0f;
    const float Aa = (gate == 2) ? 2.0f : 1.0f;
    const float Ba = (gate == 2) ? -1.0f : 0.0f;

    const float4* hq = reinterpret_cast<const float4*>(h_s + (gate << 6));

    const int* __restrict__ xrow = x + (long)b * T;

    float h = 0.0f;   // lane's h value (replicated across all 4 waves)
    float c = 0.0f;

    int   tok_next = (T > 1) ? xrow[1] : 0;
    float p_cur    = Pf[xrow[0] * G4 + j];

    for (int t = 0; t < T; ++t) {
        // prefetch next timestep's projected input (L2-resident gather)
        float p_next = 0.0f;
        if (t + 1 < T) p_next = Pf[tok_next * G4 + j];
        int tok_next2 = (t + 2 < T) ? xrow[t + 2] : 0;

        // s = p_cur + sum_k w[k] * h[k]
        // h comes from the own-wave LDS copy: uniform-address ds_read_b128
        // (hardware broadcast, conflict-free), 16 reads instead of 64
        // readlanes.
        float a0 = 0, a1 = 0, a2 = 0, a3 = 0;
        #define STEP4(i) {                                      \
            float4 hv = hq[i];                                  \
            a0 = fmaf(q##i.x, hv.x, a0);                        \
            a1 = fmaf(q##i.y, hv.y, a1);                        \
            a2 = fmaf(q##i.z, hv.z, a2);                        \
            a3 = fmaf(q##i.w, hv.w, a3); }
        STEP4(0)  STEP4(1)  STEP4(2)  STEP4(3)
        STEP4(4)  STEP4(5)  STEP4(6)  STEP4(7)
        STEP4(8)  STEP4(9)  STEP4(10) STEP4(11)
        STEP4(12) STEP4(13) STEP4(14) STEP4(15)
        #undef STEP4

        float s   = p_cur + ((a0 + a1) + (a2 + a3));
        float act = fmaf(Aa, sigm(ms * s), Ba);

        const int ph = t & 1;
        g_s[ph][j] = act;
        __syncthreads();   // the single per-step barrier (gate exchange)

        float gi = g_s[ph][lane];
        float gf = g_s[ph][H   + lane];
        float gg = g_s[ph][2*H + lane];
        float go = g_s[ph][3*H + lane];
        c = fmaf(gf, c, gi * gg);
        h = go * tanh_s(c);

        // publish h to the own-wave copy; next iteration's hq[] reads are
        // same-wave RAW on LDS -> ordered by lgkmcnt, no barrier needed.
        h_s[(gate << 6) + lane] = h;

        p_cur    = p_next;
        tok_next = tok_next2;
    }

    __syncthreads();   // protect g_s[0] reuse below

    // backward LSTM: exactly one step (hs_b[0]) with zero initial state
    {
        int   tokL = xrow[T - 1];
        float gb   = Pb[tokL * G4 + j];
        g_s[0][j]  = fmaf(Aa, sigm(ms * gb), Ba);
    }
    if (gate == 0) hf_s[lane] = h;
    __syncthreads();

    if (j < H) {
        float i_ = g_s[0][j];
        float gg = g_s[0][2*H + j];
        float go = g_s[0][3*H + j];
        float cb = i_ * gg;               // f*c0 = 0
        hb_s[j] = go * tanh_s(cb);
    }
    __syncthreads();

    // final FC: y[b, j] = b_fc[j] + [h_f | h_b] . w_fc[j]
    if (j < 12) {
        float acc = b_fc[j];
        const float* wf = w_fc + j * (2 * H);
        #pragma unroll
        for (int k = 0; k < H; ++k) acc = fmaf(hf_s[k], wf[k], acc);
        #pragma unroll
        for (int k = 0; k < H; ++k) acc = fmaf(hb_s[k], wf[H + k], acc);
        out[b * 12 + j] = acc;
    }
}

extern "C" void kernel_launch(void* const* d_in, const int* in_sizes, int n_in,
                              void* d_out, int out_size, void* d_ws, size_t ws_size,
                              hipStream_t stream)
{
    const int*   x      = (const int*)  d_in[0];
    const float* emb    = (const float*)d_in[1];
    const float* w_ih_f = (const float*)d_in[2];
    const float* w_hh_f = (const float*)d_in[3];
    const float* b_ih_f = (const float*)d_in[4];
    const float* b_hh_f = (const float*)d_in[5];
    const float* w_ih_b = (const float*)d_in[6];
    // d_in[7] = w_hh_b (unused: backward runs exactly one step from zero state)
    const float* b_ih_b = (const float*)d_in[8];
    const float* b_hh_b = (const float*)d_in[9];
    const float* w_fc   = (const float*)d_in[10];
    const float* b_fc   = (const float*)d_in[11];
    float* out = (float*)d_out;

    const int B = out_size / 12;
    const int T = in_sizes[0] / B;
    const int V = in_sizes[1] / H;

    float* Pf = (float*)d_ws;                   // [V,4H]
    float* Pb = Pf + (size_t)V * G4;            // [V,4H]  (4 MB total)

    int pblocks = (V + 7) / 8;
    dim3 pgrid(pblocks, 2);
    proj_kernel<<<pgrid, 256, 0, stream>>>(emb, w_ih_f, b_ih_f, b_hh_f,
                                           w_ih_b, b_ih_b, b_hh_b, Pf, Pb, V);
    lstm_kernel<<<B, 256, 0, stream>>>(x, Pf, Pb, w_hh_f, w_fc, b_fc, out, T);
}